// Round 1
// baseline (20.500 us; speedup 1.0000x reference)
//
#include <hip/hip_runtime.h>

// predictions: [B=64, T=8192, D=64] f32 ; start_timestamp: int32 scalar (device)
// loss = sum_{b, j in [s,s+L), d} (p[b,j+1,d]-p[b,j,d])^2 / B - 0.5
// L = 4096, INHERENT_NEIGHBORHOOD = 0.5

#define BATCH 64
#define TDIM  8192
#define DDIM  64
#define LWIN  4096

// float4 geometry
#define D4        (DDIM / 4)        // 16 float4 per row
#define WIN4      (LWIN * D4)       // 65536 float4 per-batch window
#define WIN4_LOG2 16
#define TD4       (TDIM * D4)       // 131072 float4 per-batch full span

#define NBLOCKS 2048
#define NTHREADS 256

__global__ __launch_bounds__(NTHREADS) void nl_partial_kernel(
    const float4* __restrict__ pred, const int* __restrict__ s_ptr,
    float* __restrict__ partial) {
    const int s = *s_ptr;
    const int total = BATCH * WIN4;              // 4,194,304 float4 diffs
    const int stride = gridDim.x * blockDim.x;

    float acc = 0.0f;
    for (int v = blockIdx.x * blockDim.x + threadIdx.x; v < total; v += stride) {
        const int b = v >> WIN4_LOG2;            // v / 65536
        const int r = v & (WIN4 - 1);            // v % 65536
        const int a4 = b * TD4 + s * D4 + r;     // float4 index, max ~8.4M (fits int)
        const float4 p0 = pred[a4];
        const float4 p1 = pred[a4 + D4];         // next row j+1 (L2 hit for neighbor)
        const float dx = p1.x - p0.x;
        const float dy = p1.y - p0.y;
        const float dz = p1.z - p0.z;
        const float dw = p1.w - p0.w;
        acc += dx * dx + dy * dy + dz * dz + dw * dw;
    }

    // wave64 reduce
    #pragma unroll
    for (int off = 32; off > 0; off >>= 1) acc += __shfl_down(acc, off, 64);

    __shared__ float smem[NTHREADS / 64];
    const int lane = threadIdx.x & 63;
    const int wid  = threadIdx.x >> 6;
    if (lane == 0) smem[wid] = acc;
    __syncthreads();
    if (threadIdx.x == 0) {
        float bs = 0.0f;
        #pragma unroll
        for (int w = 0; w < NTHREADS / 64; ++w) bs += smem[w];
        partial[blockIdx.x] = bs;
    }
}

__global__ __launch_bounds__(NTHREADS) void nl_final_kernel(
    const float* __restrict__ partial, float* __restrict__ out) {
    float acc = 0.0f;
    for (int i = threadIdx.x; i < NBLOCKS; i += NTHREADS) acc += partial[i];

    #pragma unroll
    for (int off = 32; off > 0; off >>= 1) acc += __shfl_down(acc, off, 64);

    __shared__ float smem[NTHREADS / 64];
    const int lane = threadIdx.x & 63;
    const int wid  = threadIdx.x >> 6;
    if (lane == 0) smem[wid] = acc;
    __syncthreads();
    if (threadIdx.x == 0) {
        float total = 0.0f;
        #pragma unroll
        for (int w = 0; w < NTHREADS / 64; ++w) total += smem[w];
        out[0] = total / (float)BATCH - 0.5f;    // INHERENT_NEIGHBORHOOD
    }
}

extern "C" void kernel_launch(void* const* d_in, const int* in_sizes, int n_in,
                              void* d_out, int out_size, void* d_ws, size_t ws_size,
                              hipStream_t stream) {
    const float4* pred = (const float4*)d_in[0];
    const int* s_ptr   = (const int*)d_in[1];
    float* out         = (float*)d_out;
    float* partial     = (float*)d_ws;           // NBLOCKS floats = 8 KB

    nl_partial_kernel<<<NBLOCKS, NTHREADS, 0, stream>>>(pred, s_ptr, partial);
    nl_final_kernel<<<1, NTHREADS, 0, stream>>>(partial, out);
}